// Round 9
// baseline (123.435 us; speedup 1.0000x reference)
//
#include <hip/hip_runtime.h>

// out = F_amp(MLP(z_i, z_j, sep_xy2)) * (dxy / sep_r2)
// Theory: all prior variants floor at the per-element SCALAR-MEMORY weight
// stream (241 weight floats can't persist in ~102 SGPRs -> s_load re-fetch
// per element ~ 1210 cyc/pair, invariant to VALU count: R3/R4/R6 all ~69us).
// Fix: (a) 4 elements/thread -- each weight s_load feeds 4 packed FMAs;
// (b) weights packed in d_ws with rows PADDED TO 16 FLOATS so the 5 pair
// loads per row merge into aligned s_load_dwordx8+dwordx2.
// Neuron-pair packing + free activation splat via VOP3P op_sel (proven R6/R7).

typedef float f32x4 __attribute__((ext_vector_type(4)));
typedef float f32x2 __attribute__((ext_vector_type(2)));

// d = splat(a[half]) * w + c ; w pinned to SGPR pair (1 SGPR src is legal)
__device__ __forceinline__ f32x2 pkfma_lo(f32x2 a, f32x2 w, f32x2 c) {
    f32x2 d;
    asm("v_pk_fma_f32 %0, %1, %2, %3 op_sel:[0,0,0] op_sel_hi:[0,1,1]"
        : "=v"(d) : "v"(a), "s"(w), "v"(c));
    return d;
}
__device__ __forceinline__ f32x2 pkfma_hi(f32x2 a, f32x2 w, f32x2 c) {
    f32x2 d;
    asm("v_pk_fma_f32 %0, %1, %2, %3 op_sel:[1,0,0] op_sel_hi:[1,1,1]"
        : "=v"(d) : "v"(a), "s"(w), "v"(c));
    return d;
}

__device__ __forceinline__ f32x2 fma2(f32x2 a, f32x2 b, f32x2 c) {
    return __builtin_elementwise_fma(a, b, c);
}

__device__ __forceinline__ f32x2 lrelu2(f32x2 x) {
    return __builtin_elementwise_max(x, x * 0.1f);   // alpha=0.1
}

__device__ __forceinline__ f32x2 tanh2(f32x2 x) {
    // tanh = 1 - 2/(exp2(x*2log2e)+1); pk_mul/pk_add/pk_fma + 2x(exp,rcp)
    f32x2 t = x * 2.8853900817779268f;
    f32x2 e;
    e[0] = __builtin_amdgcn_exp2f(t[0]);
    e[1] = __builtin_amdgcn_exp2f(t[1]);
    f32x2 ep = e + 1.0f;
    f32x2 r;
    r[0] = __builtin_amdgcn_rcpf(ep[0]);
    r[1] = __builtin_amdgcn_rcpf(ep[1]);
    return fma2((f32x2){-2.0f, -2.0f}, r, (f32x2){1.0f, 1.0f});
}

// packed d_ws layout (float offsets); W rows padded to 16 floats
#define OW1 0      // 3 rows @ 16
#define OB1 48
#define OW2 64     // 10 rows @ 16
#define OB2 224
#define OW3 240    // 10 rows @ 16
#define OB3 400
#define OW4 416
#define OB4 432

#define NE 4   // elements per thread (= 2 input pairs)

__global__ void __launch_bounds__(256) fused_mlp_kernel(
    const float* __restrict__ in, const float* __restrict__ wp,
    float* __restrict__ out, int npairs)
{
    int tid = blockIdx.x * blockDim.x + threadIdx.x;
    int p0 = 2 * tid;
    if (p0 >= npairs) return;
    int p1 = p0 + 1;
    bool v1 = (p1 < npairs);
    int q1 = v1 ? p1 : p0;

    const f32x4* in4 = reinterpret_cast<const f32x4*>(in);
    f32x4 A0 = in4[3 * p0 + 0];
    f32x4 B0 = in4[3 * p0 + 1];
    f32x4 C0 = in4[3 * p0 + 2];
    f32x4 A1 = in4[3 * q1 + 0];
    f32x4 B1 = in4[3 * q1 + 1];
    f32x4 C1 = in4[3 * q1 + 2];

    float xs[NE][6] = {
        {A0[0], A0[1], A0[2], A0[3], B0[0], B0[1]},
        {B0[2], B0[3], C0[0], C0[1], C0[2], C0[3]},
        {A1[0], A1[1], A1[2], A1[3], B1[0], B1[1]},
        {B1[2], B1[3], C1[0], C1[1], C1[2], C1[3]}
    };

    // features
    float dxe[NE], dye[NE], inve[NE];
    f32x2 zAB[NE], zC2[NE];
    #pragma unroll
    for (int e = 0; e < NE; ++e) {
        float dx = xs[e][3] - xs[e][0];
        float dy = xs[e][4] - xs[e][1];
        float dz = xs[e][5] - xs[e][2];
        float sep_xy2 = fmaf(dx, dx, dy * dy);
        float sep_r2  = fmaf(dz, dz, sep_xy2);
        dxe[e] = dx; dye[e] = dy;
        inve[e] = __builtin_amdgcn_rcpf(sep_r2);
        f32x2 t; t[0] = xs[e][2]; t[1] = xs[e][5];   // {z_i, z_j}
        zAB[e] = t;
        f32x2 u; u[0] = sep_xy2; u[1] = sep_xy2;
        zC2[e] = u;
    }

    const f32x2* wp2 = reinterpret_cast<const f32x2*>(wp);
#define LP(off) (wp2[(off) >> 1])

    // ---- Layer 1: [3]->[10], leaky relu. One weight fetch feeds NE FMAs.
    f32x2 h[NE][5];
    #pragma unroll
    for (int jp = 0; jp < 5; ++jp) {
        f32x2 w0 = LP(OW1 + 0  + 2 * jp);
        f32x2 w1 = LP(OW1 + 16 + 2 * jp);
        f32x2 w2 = LP(OW1 + 32 + 2 * jp);
        f32x2 bb = LP(OB1 + 2 * jp);
        #pragma unroll
        for (int e = 0; e < NE; ++e) {
            f32x2 a = pkfma_lo(zAB[e], w0, bb);
            a = pkfma_hi(zAB[e], w1, a);
            a = pkfma_lo(zC2[e], w2, a);
            h[e][jp] = lrelu2(a);
        }
    }

    // ---- Layer 2: [10]->[10], tanh
    f32x2 acc[NE][5];
    #pragma unroll
    for (int jp = 0; jp < 5; ++jp) {
        f32x2 bb = LP(OB2 + 2 * jp);
        #pragma unroll
        for (int e = 0; e < NE; ++e) acc[e][jp] = bb;
    }
    #pragma unroll
    for (int i = 0; i < 10; ++i) {
        #pragma unroll
        for (int jp = 0; jp < 5; ++jp) {
            f32x2 w = LP(OW2 + 16 * i + 2 * jp);
            #pragma unroll
            for (int e = 0; e < NE; ++e) {
                if (i & 1) acc[e][jp] = pkfma_hi(h[e][i >> 1], w, acc[e][jp]);
                else       acc[e][jp] = pkfma_lo(h[e][i >> 1], w, acc[e][jp]);
            }
        }
    }
    #pragma unroll
    for (int e = 0; e < NE; ++e)
        #pragma unroll
        for (int jp = 0; jp < 5; ++jp) h[e][jp] = tanh2(acc[e][jp]);

    // ---- Layer 3: [10]->[10], leaky relu
    #pragma unroll
    for (int jp = 0; jp < 5; ++jp) {
        f32x2 bb = LP(OB3 + 2 * jp);
        #pragma unroll
        for (int e = 0; e < NE; ++e) acc[e][jp] = bb;
    }
    #pragma unroll
    for (int i = 0; i < 10; ++i) {
        #pragma unroll
        for (int jp = 0; jp < 5; ++jp) {
            f32x2 w = LP(OW3 + 16 * i + 2 * jp);
            #pragma unroll
            for (int e = 0; e < NE; ++e) {
                if (i & 1) acc[e][jp] = pkfma_hi(h[e][i >> 1], w, acc[e][jp]);
                else       acc[e][jp] = pkfma_lo(h[e][i >> 1], w, acc[e][jp]);
            }
        }
    }
    #pragma unroll
    for (int e = 0; e < NE; ++e)
        #pragma unroll
        for (int jp = 0; jp < 5; ++jp) h[e][jp] = lrelu2(acc[e][jp]);

    // ---- Layer 4: [10]->[1]
    float b4v = wp[OB4];
    float fa[NE];
    #pragma unroll
    for (int e = 0; e < NE; ++e) {
        f32x2 f = {b4v, 0.0f};
        #pragma unroll
        for (int ip = 0; ip < 5; ++ip)
            f = fma2(h[e][ip], LP(OW4 + 2 * ip), f);
        fa[e] = f[0] + f[1];
    }

    f32x4* out4 = reinterpret_cast<f32x4*>(out);
    {
        float s0 = fa[0] * inve[0];
        float s1 = fa[1] * inve[1];
        f32x4 o;
        o[0] = s0 * dxe[0]; o[1] = s0 * dye[0];
        o[2] = s1 * dxe[1]; o[3] = s1 * dye[1];
        out4[p0] = o;
    }
    if (v1) {
        float s2 = fa[2] * inve[2];
        float s3 = fa[3] * inve[3];
        f32x4 o;
        o[0] = s2 * dxe[2]; o[1] = s2 * dye[2];
        o[2] = s3 * dxe[3]; o[3] = s3 * dye[3];
        out4[p1] = o;
    }
#undef LP
}

extern "C" void kernel_launch(void* const* d_in, const int* in_sizes, int n_in,
                              void* d_out, int out_size, void* d_ws, size_t ws_size,
                              hipStream_t stream) {
    const float* in = (const float*)d_in[0];
    float* wsf = (float*)d_ws;

    // pack into d_ws; W-matrix rows padded to 16 floats (aligned wide s_loads)
    const float* W1 = (const float*)d_in[1];
    const float* b1 = (const float*)d_in[2];
    const float* W2 = (const float*)d_in[3];
    const float* b2 = (const float*)d_in[4];
    const float* W3 = (const float*)d_in[5];
    const float* b3 = (const float*)d_in[6];
    const float* W4 = (const float*)d_in[7];
    const float* b4 = (const float*)d_in[8];

    for (int r = 0; r < 3; ++r)
        hipMemcpyAsync(wsf + OW1 + 16 * r, W1 + 10 * r, 10 * sizeof(float),
                       hipMemcpyDeviceToDevice, stream);
    hipMemcpyAsync(wsf + OB1, b1, 10 * sizeof(float), hipMemcpyDeviceToDevice, stream);
    for (int r = 0; r < 10; ++r)
        hipMemcpyAsync(wsf + OW2 + 16 * r, W2 + 10 * r, 10 * sizeof(float),
                       hipMemcpyDeviceToDevice, stream);
    hipMemcpyAsync(wsf + OB2, b2, 10 * sizeof(float), hipMemcpyDeviceToDevice, stream);
    for (int r = 0; r < 10; ++r)
        hipMemcpyAsync(wsf + OW3 + 16 * r, W3 + 10 * r, 10 * sizeof(float),
                       hipMemcpyDeviceToDevice, stream);
    hipMemcpyAsync(wsf + OB3, b3, 10 * sizeof(float), hipMemcpyDeviceToDevice, stream);
    hipMemcpyAsync(wsf + OW4, W4, 10 * sizeof(float), hipMemcpyDeviceToDevice, stream);
    hipMemcpyAsync(wsf + OB4, b4, 1 * sizeof(float), hipMemcpyDeviceToDevice, stream);

    float* out = (float*)d_out;
    int npairs = out_size / 4;                    // 2 elements per pair
    int nthreads = (npairs + 1) / 2;              // 2 pairs (4 elems) / thread
    int blocks = (nthreads + 255) / 256;
    fused_mlp_kernel<<<blocks, 256, 0, stream>>>(in, wsf, out, npairs);
}